// Round 7
// baseline (226.697 us; speedup 1.0000x reference)
//
#include <hip/hip_runtime.h>
#include <stdint.h>

#define NROWS 262144
#define INF   64
#define HIDN  256
#define OUTM  60
#define BLOCKS 512
#define BLOCK  512                 // 8 waves; 64KB LDS -> 2 blocks/CU = 16 waves/CU

typedef __attribute__((ext_vector_type(8))) short bf16x8;
typedef __attribute__((ext_vector_type(4))) float f32x4;

// 2x f32 -> packed bf16 (RNE), 1 instruction
__device__ __forceinline__ uint32_t pk2(float lo, float hi) {
  uint32_t r;
  asm("v_cvt_pk_bf16_f32 %0, %1, %2" : "=v"(r) : "v"(lo), "v"(hi));
  return r;
}

union U8 { uint32_t u[4]; bf16x8 v; uint4 q; };

// ---------------------------------------------------------------------------
// Fused kernel: quat (Jacobi, 1 lane/row) + 2-layer MLP (bf16 MFMA, transposed
// formulation). Each wave handles 64 rows: 4 MFMA row-tiles of 16; each lane
// does the Jacobi for one of the 64 rows.
// LDS: W1T [256 hid][64 in] bf16 @0 (row=128B), W2T [64 outcol][256 hid] bf16
// @32768 (row=512B, rows 0-3 zeros -> out cols 0-3 come from quat), both
// XOR-swizzled by ((row&7)<<4) on 16B units.
// Block = 512 threads (8 waves) sharing one LDS image: occupancy cap 16
// waves/CU (VGPR-alloc 128 cap) vs 8 with 256-thread blocks.  [round-4 fix]
// ---------------------------------------------------------------------------
__global__ __launch_bounds__(BLOCK, 4)
void veronese_fused(const float* __restrict__ z,  const float* __restrict__ W1,
                    const float* __restrict__ b1, const float* __restrict__ W2,
                    const float* __restrict__ b2, float* __restrict__ out) {
  __shared__ __align__(16) uint8_t lds[65536];
  const int tid = threadIdx.x;

  // ---- stage W1T: 2 threads per hid row, 4x16B chunks each ----
  {
    const int hid  = tid & 255;
    const int half = tid >> 8;          // 0/1
    #pragma unroll
    for (int cc = 0; cc < 4; ++cc) {
      const int hc = half * 4 + cc;     // 16B chunk index (8 in-values)
      float f[8];
      #pragma unroll
      for (int j = 0; j < 8; ++j) f[j] = W1[(hc*8 + j) * HIDN + hid];
      U8 u;
      u.u[0] = pk2(f[0], f[1]); u.u[1] = pk2(f[2], f[3]);
      u.u[2] = pk2(f[4], f[5]); u.u[3] = pk2(f[6], f[7]);
      uint32_t off = (uint32_t)hid * 128 + (uint32_t)((hc * 16) ^ ((hid & 7) << 4));
      *reinterpret_cast<uint4*>(lds + off) = u.q;
    }
  }
  // ---- stage W2T: 8 threads per out row, 4x16B chunks each; rows 0-3 zero ----
  {
    const int o   = tid & 63;
    const int seg = tid >> 6;           // 0..7
    #pragma unroll
    for (int uu = 0; uu < 4; ++uu) {
      const int hb = seg * 32 + uu * 8; // hid base of this 16B chunk
      float f[8];
      #pragma unroll
      for (int j = 0; j < 8; ++j)
        f[j] = (o >= 4) ? W2[(hb + j) * OUTM + (o - 4)] : 0.0f;
      U8 u;
      u.u[0] = pk2(f[0], f[1]); u.u[1] = pk2(f[2], f[3]);
      u.u[2] = pk2(f[4], f[5]); u.u[3] = pk2(f[6], f[7]);
      uint32_t off = 32768u + (uint32_t)o * 512 + (uint32_t)((hb * 2) ^ ((o & 7) << 4));
      *reinterpret_cast<uint4*>(lds + off) = u.q;
    }
  }
  __syncthreads();

  const int l   = tid & 63;
  const int w   = tid >> 6;             // 0..7
  const int g   = l >> 4;
  const int l15 = l & 15;
  const uint32_t swz = (uint32_t)((l & 7) << 4);
  // 4-slot exchange lane addresses (verified round 3)
  const int srcA = l15 + 32*(g & 1) + 16*(g >> 1);
  const int srcB = l15 + 32*(g & 1) + 16*(1 - (g >> 1));
  const bool hiq = (g & 2) != 0;
  const bool amI16 = (l & 16) != 0;

  // bias2: out col = 16m+4g; col<4 is the quat slot (zero bias)
  f32x4 bias2[4];
  #pragma unroll
  for (int m = 0; m < 4; ++m) {
    int ob = 16*m + 4*g;
    if (ob >= 4) bias2[m] = *reinterpret_cast<const f32x4*>(b2 + ob - 4);
    else         bias2[m] = (f32x4){0.f, 0.f, 0.f, 0.f};
  }

  const int rowBase = blockIdx.x * BLOCK + w * 64;

  // ---- z loads: quat row (this lane) + 4 MFMA B-frag tiles ----
  const float* zq = z + (size_t)(rowBase + l) * INF;
  float4 qv0 = reinterpret_cast<const float4*>(zq)[0];
  float4 qv1 = reinterpret_cast<const float4*>(zq)[1];
  float4 qv2 = reinterpret_cast<const float4*>(zq)[2];

  bf16x8 zf[4][2];
  #pragma unroll
  for (int t = 0; t < 4; ++t) {
    const float* zp = z + (size_t)(rowBase + 16*t + l15) * INF;
    #pragma unroll
    for (int k1 = 0; k1 < 2; ++k1) {
      float4 a0 = *reinterpret_cast<const float4*>(zp + k1*32 + 8*g);
      float4 a1 = *reinterpret_cast<const float4*>(zp + k1*32 + 8*g + 4);
      U8 u;
      u.u[0] = pk2(a0.x, a0.y); u.u[1] = pk2(a0.z, a0.w);
      u.u[2] = pk2(a1.x, a1.y); u.u[3] = pk2(a1.z, a1.w);
      zf[t][k1] = u.v;
    }
  }

  // ---- quat: branchless Jacobi, native transcendentals, 6 sweeps ----
  float q0, q1, q2, q3;
  {
    float zv[10] = {qv0.x,qv0.y,qv0.z,qv0.w, qv1.x,qv1.y,qv1.z,qv1.w,
                    qv2.x,qv2.y};
    float M[4][4];
    M[0][0]=zv[0]; M[0][1]=zv[1]; M[0][2]=zv[2]; M[0][3]=zv[3];
    M[1][1]=zv[4]; M[1][2]=zv[5]; M[1][3]=zv[6];
    M[2][2]=zv[7]; M[2][3]=zv[8]; M[3][3]=zv[9];
    M[1][0]=zv[1]; M[2][0]=zv[2]; M[3][0]=zv[3];
    M[2][1]=zv[5]; M[3][1]=zv[6]; M[3][2]=zv[8];
    float V[4][4] = {{1.f,0.f,0.f,0.f},{0.f,1.f,0.f,0.f},
                     {0.f,0.f,1.f,0.f},{0.f,0.f,0.f,1.f}};

#define JROT(p, q) do {                                                      \
    float apq = M[p][q];                                                     \
    float app = M[p][p], aqq = M[q][q];                                      \
    float tau = (aqq - app) * (0.5f * __builtin_amdgcn_rcpf(apq));           \
    float t_r = copysignf(1.0f, tau) *                                       \
        __builtin_amdgcn_rcpf(fabsf(tau) +                                   \
            __builtin_amdgcn_sqrtf(fmaf(tau, tau, 1.0f)));                   \
    float t   = (fabsf(apq) > 1e-25f) ? t_r : 0.0f;                          \
    float c   = __builtin_amdgcn_rsqf(fmaf(t, t, 1.0f));                     \
    float s   = t * c;                                                       \
    M[p][p] = fmaf(-t, apq, app);                                            \
    M[q][q] = fmaf( t, apq, aqq);                                            \
    M[p][q] = 0.0f; M[q][p] = 0.0f;                                          \
    _Pragma("unroll")                                                        \
    for (int r = 0; r < 4; ++r) {                                            \
      if (r != p && r != q) {                                                \
        float arp = M[r][p], arq = M[r][q];                                  \
        float nrp = fmaf(-s, arq, c * arp);                                  \
        float nrq = fmaf( s, arp, c * arq);                                  \
        M[r][p] = nrp; M[p][r] = nrp;                                        \
        M[r][q] = nrq; M[q][r] = nrq;                                        \
      }                                                                      \
    }                                                                        \
    _Pragma("unroll")                                                        \
    for (int r = 0; r < 4; ++r) {                                            \
      float vrp = V[r][p], vrq = V[r][q];                                    \
      V[r][p] = fmaf(-s, vrq, c * vrp);                                      \
      V[r][q] = fmaf( s, vrp, c * vrq);                                      \
    }                                                                        \
  } while (0)

    #pragma unroll
    for (int sweep = 0; sweep < 6; ++sweep) {
      JROT(0, 1); JROT(0, 2); JROT(0, 3);
      JROT(1, 2); JROT(1, 3); JROT(2, 3);
    }
#undef JROT

    float bv = M[0][0];
    q0 = V[0][0]; q1 = V[1][0]; q2 = V[2][0]; q3 = V[3][0];
    #pragma unroll
    for (int j = 1; j < 4; ++j) {
      float dj = M[j][j];
      bool  b  = dj > bv;
      bv = b ? dj      : bv;
      q0 = b ? V[0][j] : q0;
      q1 = b ? V[1][j] : q1;
      q2 = b ? V[2][j] : q2;
      q3 = b ? V[3][j] : q3;
    }
    float sgn = (q0 < 0.0f) ? -1.0f : 1.0f;  // sign(0) -> +1
    q0 *= sgn; q1 *= sgn; q2 *= sgn; q3 *= sgn;
  }

  // ---- MLP ----
  f32x4 acc2[4][4];
  #pragma unroll
  for (int t = 0; t < 4; ++t)
    #pragma unroll
    for (int m = 0; m < 4; ++m) acc2[t][m] = bias2[m];

  for (int ks = 0; ks < 8; ++ks) {
    uint32_t c[4][4];
    // layer 1, two hid m-tiles (mm), A-frags shared across the 4 z-tiles
    #pragma unroll
    for (int mm = 0; mm < 2; ++mm) {
      const int hb = 16*(2*ks + mm) + 4*g;
      f32x4 bv = *reinterpret_cast<const f32x4*>(b1 + hb);   // L1-hot
      uint32_t rowb = (uint32_t)(16*(2*ks+mm) + l15) * 128;
      bf16x8 a0 = *reinterpret_cast<const bf16x8*>(
          lds + rowb + (((uint32_t)(16*g)) ^ swz));
      bf16x8 a1 = *reinterpret_cast<const bf16x8*>(
          lds + rowb + (((uint32_t)(64 + 16*g)) ^ swz));
      f32x4 acc1[4];
      __builtin_amdgcn_s_setprio(1);
      #pragma unroll
      for (int t = 0; t < 4; ++t) {
        acc1[t] = __builtin_amdgcn_mfma_f32_16x16x32_bf16(a0, zf[t][0], bv, 0,0,0);
        acc1[t] = __builtin_amdgcn_mfma_f32_16x16x32_bf16(a1, zf[t][1], acc1[t], 0,0,0);
      }
      __builtin_amdgcn_s_setprio(0);
      #pragma unroll
      for (int t = 0; t < 4; ++t) {
        float h0 = fmaxf(acc1[t][0], 0.f), h1 = fmaxf(acc1[t][1], 0.f);
        float h2 = fmaxf(acc1[t][2], 0.f), h3 = fmaxf(acc1[t][3], 0.f);
        c[t][2*mm+0] = pk2(h0, h1);
        c[t][2*mm+1] = pk2(h2, h3);
      }
    }
    // layer-2 A-frags (shared across tiles)
    bf16x8 a2[4];
    #pragma unroll
    for (int m = 0; m < 4; ++m) {
      uint32_t rowb = 32768u + (uint32_t)(16*m + l15) * 512;
      a2[m] = *reinterpret_cast<const bf16x8*>(
          lds + rowb + (((uint32_t)(64*ks + 16*g)) ^ swz));
    }
    // exchange + layer 2 per tile: 4 shuffles (slot scheme), 8 cndmask
    #pragma unroll
    for (int t = 0; t < 4; ++t) {
      uint32_t v02a = amI16 ? c[t][2] : c[t][0];
      uint32_t v13a = amI16 ? c[t][3] : c[t][1];
      uint32_t v02b = amI16 ? c[t][0] : c[t][2];
      uint32_t v13b = amI16 ? c[t][1] : c[t][3];
      uint32_t s0 = (uint32_t)__shfl((int)v02a, srcA, 64);
      uint32_t s1 = (uint32_t)__shfl((int)v13a, srcA, 64);
      uint32_t s2 = (uint32_t)__shfl((int)v02b, srcB, 64);
      uint32_t s3 = (uint32_t)__shfl((int)v13b, srcB, 64);
      U8 bu;
      bu.u[0] = hiq ? s2 : s0;
      bu.u[1] = hiq ? s3 : s1;
      bu.u[2] = hiq ? s0 : s2;
      bu.u[3] = hiq ? s1 : s3;
      __builtin_amdgcn_s_setprio(1);
      #pragma unroll
      for (int m = 0; m < 4; ++m)
        acc2[t][m] = __builtin_amdgcn_mfma_f32_16x16x32_bf16(a2[m], bu.v, acc2[t][m], 0,0,0);
      __builtin_amdgcn_s_setprio(0);
    }
  }

  // ---- inject quat into out cols 0-3 (g==0 lanes, acc2[t][0]) ----
  #pragma unroll
  for (int t = 0; t < 4; ++t) {
    int src = 16*t + l15;
    float v0 = __shfl(q0, src, 64);
    float v1 = __shfl(q1, src, 64);
    float v2 = __shfl(q2, src, 64);
    float v3 = __shfl(q3, src, 64);
    if (g == 0) {
      acc2[t][0][0] = v0; acc2[t][0][1] = v1;
      acc2[t][0][2] = v2; acc2[t][0][3] = v3;
    }
  }

  // ---- store: 16 full float4s per row -> full 256B lines, no RMW ----
  #pragma unroll
  for (int t = 0; t < 4; ++t) {
    float* op = out + (size_t)(rowBase + 16*t + l15) * 64;
    #pragma unroll
    for (int m = 0; m < 4; ++m) {
      float4 v = make_float4(acc2[t][m][0], acc2[t][m][1],
                             acc2[t][m][2], acc2[t][m][3]);
      *reinterpret_cast<float4*>(op + 16*m + 4*g) = v;
    }
  }
}

extern "C" void kernel_launch(void* const* d_in, const int* in_sizes, int n_in,
                              void* d_out, int out_size, void* d_ws, size_t ws_size,
                              hipStream_t stream) {
  const float* z  = (const float*)d_in[0];
  const float* W1 = (const float*)d_in[1];
  const float* b1 = (const float*)d_in[2];
  const float* W2 = (const float*)d_in[3];
  const float* b2 = (const float*)d_in[4];
  float* out = (float*)d_out;

  hipLaunchKernelGGL(veronese_fused, dim3(BLOCKS), dim3(BLOCK), 0, stream,
                     z, W1, b1, W2, b2, out);
}

// Round 8
// 151.500 us; speedup vs baseline: 1.4964x; 1.4964x over previous
//
#include <hip/hip_runtime.h>
#include <stdint.h>

#define NROWS 262144
#define INF   64
#define HIDN  256
#define OUTM  60
#define BLOCKS 512
#define BLOCK  512                 // 8 waves; 64KB LDS -> 2 blocks/CU = 16 waves/CU

typedef __attribute__((ext_vector_type(8))) short bf16x8;
typedef __attribute__((ext_vector_type(4))) float f32x4;

// 2x f32 -> packed bf16 (RNE), 1 instruction
__device__ __forceinline__ uint32_t pk2(float lo, float hi) {
  uint32_t r;
  asm("v_cvt_pk_bf16_f32 %0, %1, %2" : "=v"(r) : "v"(lo), "v"(hi));
  return r;
}

union U8 { uint32_t u[4]; bf16x8 v; uint4 q; };

// ---------------------------------------------------------------------------
// Fused kernel: quat (Jacobi, 1 lane/row) + 2-layer MLP (bf16 MFMA, transposed
// formulation). Each wave handles 64 rows: 4 MFMA row-tiles of 16; each lane
// does the Jacobi for one of the 64 rows.
// LDS: W1T [256 hid][64 in] bf16 @0 (row=128B), W2T [64 outcol][256 hid] bf16
// @32768 (row=512B, rows 0-3 zeros -> out cols 0-3 come from quat), both
// XOR-swizzled by ((row&7)<<4) on 16B units.
// __launch_bounds__(512, 2): R7's (512,4) capped VGPR at 64 -> ~280MB scratch
// spill traffic, 2x regression. Arg 2 allows ~128 VGPR (kernel needs ~120,
// R4-measured) while LDS still permits 2 blocks/CU = 16 waves/CU. [R7 fix]
// ---------------------------------------------------------------------------
__global__ __launch_bounds__(BLOCK, 2)
void veronese_fused(const float* __restrict__ z,  const float* __restrict__ W1,
                    const float* __restrict__ b1, const float* __restrict__ W2,
                    const float* __restrict__ b2, float* __restrict__ out) {
  __shared__ __align__(16) uint8_t lds[65536];
  const int tid = threadIdx.x;

  // ---- stage W1T: 2 threads per hid row, 4x16B chunks each ----
  {
    const int hid  = tid & 255;
    const int half = tid >> 8;          // 0/1
    #pragma unroll
    for (int cc = 0; cc < 4; ++cc) {
      const int hc = half * 4 + cc;     // 16B chunk index (8 in-values)
      float f[8];
      #pragma unroll
      for (int j = 0; j < 8; ++j) f[j] = W1[(hc*8 + j) * HIDN + hid];
      U8 u;
      u.u[0] = pk2(f[0], f[1]); u.u[1] = pk2(f[2], f[3]);
      u.u[2] = pk2(f[4], f[5]); u.u[3] = pk2(f[6], f[7]);
      uint32_t off = (uint32_t)hid * 128 + (uint32_t)((hc * 16) ^ ((hid & 7) << 4));
      *reinterpret_cast<uint4*>(lds + off) = u.q;
    }
  }
  // ---- stage W2T: 8 threads per out row, 4x16B chunks each; rows 0-3 zero ----
  {
    const int o   = tid & 63;
    const int seg = tid >> 6;           // 0..7
    #pragma unroll
    for (int uu = 0; uu < 4; ++uu) {
      const int hb = seg * 32 + uu * 8; // hid base of this 16B chunk
      float f[8];
      #pragma unroll
      for (int j = 0; j < 8; ++j)
        f[j] = (o >= 4) ? W2[(hb + j) * OUTM + (o - 4)] : 0.0f;
      U8 u;
      u.u[0] = pk2(f[0], f[1]); u.u[1] = pk2(f[2], f[3]);
      u.u[2] = pk2(f[4], f[5]); u.u[3] = pk2(f[6], f[7]);
      uint32_t off = 32768u + (uint32_t)o * 512 + (uint32_t)((hb * 2) ^ ((o & 7) << 4));
      *reinterpret_cast<uint4*>(lds + off) = u.q;
    }
  }
  __syncthreads();

  const int l   = tid & 63;
  const int w   = tid >> 6;             // 0..7
  const int g   = l >> 4;
  const int l15 = l & 15;
  const uint32_t swz = (uint32_t)((l & 7) << 4);
  // 4-slot exchange lane addresses (verified round 3)
  const int srcA = l15 + 32*(g & 1) + 16*(g >> 1);
  const int srcB = l15 + 32*(g & 1) + 16*(1 - (g >> 1));
  const bool hiq = (g & 2) != 0;
  const bool amI16 = (l & 16) != 0;

  // bias2: out col = 16m+4g; col<4 is the quat slot (zero bias)
  f32x4 bias2[4];
  #pragma unroll
  for (int m = 0; m < 4; ++m) {
    int ob = 16*m + 4*g;
    if (ob >= 4) bias2[m] = *reinterpret_cast<const f32x4*>(b2 + ob - 4);
    else         bias2[m] = (f32x4){0.f, 0.f, 0.f, 0.f};
  }

  const int rowBase = blockIdx.x * BLOCK + w * 64;

  // ---- z loads: quat row (this lane) + 4 MFMA B-frag tiles ----
  const float* zq = z + (size_t)(rowBase + l) * INF;
  float4 qv0 = reinterpret_cast<const float4*>(zq)[0];
  float4 qv1 = reinterpret_cast<const float4*>(zq)[1];
  float4 qv2 = reinterpret_cast<const float4*>(zq)[2];

  bf16x8 zf[4][2];
  #pragma unroll
  for (int t = 0; t < 4; ++t) {
    const float* zp = z + (size_t)(rowBase + 16*t + l15) * INF;
    #pragma unroll
    for (int k1 = 0; k1 < 2; ++k1) {
      float4 a0 = *reinterpret_cast<const float4*>(zp + k1*32 + 8*g);
      float4 a1 = *reinterpret_cast<const float4*>(zp + k1*32 + 8*g + 4);
      U8 u;
      u.u[0] = pk2(a0.x, a0.y); u.u[1] = pk2(a0.z, a0.w);
      u.u[2] = pk2(a1.x, a1.y); u.u[3] = pk2(a1.z, a1.w);
      zf[t][k1] = u.v;
    }
  }

  // ---- quat: branchless Jacobi, native transcendentals, 6 sweeps ----
  float q0, q1, q2, q3;
  {
    float zv[10] = {qv0.x,qv0.y,qv0.z,qv0.w, qv1.x,qv1.y,qv1.z,qv1.w,
                    qv2.x,qv2.y};
    float M[4][4];
    M[0][0]=zv[0]; M[0][1]=zv[1]; M[0][2]=zv[2]; M[0][3]=zv[3];
    M[1][1]=zv[4]; M[1][2]=zv[5]; M[1][3]=zv[6];
    M[2][2]=zv[7]; M[2][3]=zv[8]; M[3][3]=zv[9];
    M[1][0]=zv[1]; M[2][0]=zv[2]; M[3][0]=zv[3];
    M[2][1]=zv[5]; M[3][1]=zv[6]; M[3][2]=zv[8];
    float V[4][4] = {{1.f,0.f,0.f,0.f},{0.f,1.f,0.f,0.f},
                     {0.f,0.f,1.f,0.f},{0.f,0.f,0.f,1.f}};

#define JROT(p, q) do {                                                      \
    float apq = M[p][q];                                                     \
    float app = M[p][p], aqq = M[q][q];                                      \
    float tau = (aqq - app) * (0.5f * __builtin_amdgcn_rcpf(apq));           \
    float t_r = copysignf(1.0f, tau) *                                       \
        __builtin_amdgcn_rcpf(fabsf(tau) +                                   \
            __builtin_amdgcn_sqrtf(fmaf(tau, tau, 1.0f)));                   \
    float t   = (fabsf(apq) > 1e-25f) ? t_r : 0.0f;                          \
    float c   = __builtin_amdgcn_rsqf(fmaf(t, t, 1.0f));                     \
    float s   = t * c;                                                       \
    M[p][p] = fmaf(-t, apq, app);                                            \
    M[q][q] = fmaf( t, apq, aqq);                                            \
    M[p][q] = 0.0f; M[q][p] = 0.0f;                                          \
    _Pragma("unroll")                                                        \
    for (int r = 0; r < 4; ++r) {                                            \
      if (r != p && r != q) {                                                \
        float arp = M[r][p], arq = M[r][q];                                  \
        float nrp = fmaf(-s, arq, c * arp);                                  \
        float nrq = fmaf( s, arp, c * arq);                                  \
        M[r][p] = nrp; M[p][r] = nrp;                                        \
        M[r][q] = nrq; M[q][r] = nrq;                                        \
      }                                                                      \
    }                                                                        \
    _Pragma("unroll")                                                        \
    for (int r = 0; r < 4; ++r) {                                            \
      float vrp = V[r][p], vrq = V[r][q];                                    \
      V[r][p] = fmaf(-s, vrq, c * vrp);                                      \
      V[r][q] = fmaf( s, vrp, c * vrq);                                      \
    }                                                                        \
  } while (0)

    #pragma unroll
    for (int sweep = 0; sweep < 6; ++sweep) {
      JROT(0, 1); JROT(0, 2); JROT(0, 3);
      JROT(1, 2); JROT(1, 3); JROT(2, 3);
    }
#undef JROT

    float bv = M[0][0];
    q0 = V[0][0]; q1 = V[1][0]; q2 = V[2][0]; q3 = V[3][0];
    #pragma unroll
    for (int j = 1; j < 4; ++j) {
      float dj = M[j][j];
      bool  b  = dj > bv;
      bv = b ? dj      : bv;
      q0 = b ? V[0][j] : q0;
      q1 = b ? V[1][j] : q1;
      q2 = b ? V[2][j] : q2;
      q3 = b ? V[3][j] : q3;
    }
    float sgn = (q0 < 0.0f) ? -1.0f : 1.0f;  // sign(0) -> +1
    q0 *= sgn; q1 *= sgn; q2 *= sgn; q3 *= sgn;
  }

  // ---- MLP ----
  f32x4 acc2[4][4];
  #pragma unroll
  for (int t = 0; t < 4; ++t)
    #pragma unroll
    for (int m = 0; m < 4; ++m) acc2[t][m] = bias2[m];

  for (int ks = 0; ks < 8; ++ks) {
    uint32_t c[4][4];
    // layer 1, two hid m-tiles (mm), A-frags shared across the 4 z-tiles
    #pragma unroll
    for (int mm = 0; mm < 2; ++mm) {
      const int hb = 16*(2*ks + mm) + 4*g;
      f32x4 bv = *reinterpret_cast<const f32x4*>(b1 + hb);   // L1-hot
      uint32_t rowb = (uint32_t)(16*(2*ks+mm) + l15) * 128;
      bf16x8 a0 = *reinterpret_cast<const bf16x8*>(
          lds + rowb + (((uint32_t)(16*g)) ^ swz));
      bf16x8 a1 = *reinterpret_cast<const bf16x8*>(
          lds + rowb + (((uint32_t)(64 + 16*g)) ^ swz));
      f32x4 acc1[4];
      __builtin_amdgcn_s_setprio(1);
      #pragma unroll
      for (int t = 0; t < 4; ++t) {
        acc1[t] = __builtin_amdgcn_mfma_f32_16x16x32_bf16(a0, zf[t][0], bv, 0,0,0);
        acc1[t] = __builtin_amdgcn_mfma_f32_16x16x32_bf16(a1, zf[t][1], acc1[t], 0,0,0);
      }
      __builtin_amdgcn_s_setprio(0);
      #pragma unroll
      for (int t = 0; t < 4; ++t) {
        float h0 = fmaxf(acc1[t][0], 0.f), h1 = fmaxf(acc1[t][1], 0.f);
        float h2 = fmaxf(acc1[t][2], 0.f), h3 = fmaxf(acc1[t][3], 0.f);
        c[t][2*mm+0] = pk2(h0, h1);
        c[t][2*mm+1] = pk2(h2, h3);
      }
    }
    // layer-2 A-frags (shared across tiles)
    bf16x8 a2[4];
    #pragma unroll
    for (int m = 0; m < 4; ++m) {
      uint32_t rowb = 32768u + (uint32_t)(16*m + l15) * 512;
      a2[m] = *reinterpret_cast<const bf16x8*>(
          lds + rowb + (((uint32_t)(64*ks + 16*g)) ^ swz));
    }
    // exchange + layer 2 per tile: 4 shuffles (slot scheme), 8 cndmask
    #pragma unroll
    for (int t = 0; t < 4; ++t) {
      uint32_t v02a = amI16 ? c[t][2] : c[t][0];
      uint32_t v13a = amI16 ? c[t][3] : c[t][1];
      uint32_t v02b = amI16 ? c[t][0] : c[t][2];
      uint32_t v13b = amI16 ? c[t][1] : c[t][3];
      uint32_t s0 = (uint32_t)__shfl((int)v02a, srcA, 64);
      uint32_t s1 = (uint32_t)__shfl((int)v13a, srcA, 64);
      uint32_t s2 = (uint32_t)__shfl((int)v02b, srcB, 64);
      uint32_t s3 = (uint32_t)__shfl((int)v13b, srcB, 64);
      U8 bu;
      bu.u[0] = hiq ? s2 : s0;
      bu.u[1] = hiq ? s3 : s1;
      bu.u[2] = hiq ? s0 : s2;
      bu.u[3] = hiq ? s1 : s3;
      __builtin_amdgcn_s_setprio(1);
      #pragma unroll
      for (int m = 0; m < 4; ++m)
        acc2[t][m] = __builtin_amdgcn_mfma_f32_16x16x32_bf16(a2[m], bu.v, acc2[t][m], 0,0,0);
      __builtin_amdgcn_s_setprio(0);
    }
  }

  // ---- inject quat into out cols 0-3 (g==0 lanes, acc2[t][0]) ----
  #pragma unroll
  for (int t = 0; t < 4; ++t) {
    int src = 16*t + l15;
    float v0 = __shfl(q0, src, 64);
    float v1 = __shfl(q1, src, 64);
    float v2 = __shfl(q2, src, 64);
    float v3 = __shfl(q3, src, 64);
    if (g == 0) {
      acc2[t][0][0] = v0; acc2[t][0][1] = v1;
      acc2[t][0][2] = v2; acc2[t][0][3] = v3;
    }
  }

  // ---- store: 16 full float4s per row -> full 256B lines, no RMW ----
  #pragma unroll
  for (int t = 0; t < 4; ++t) {
    float* op = out + (size_t)(rowBase + 16*t + l15) * 64;
    #pragma unroll
    for (int m = 0; m < 4; ++m) {
      float4 v = make_float4(acc2[t][m][0], acc2[t][m][1],
                             acc2[t][m][2], acc2[t][m][3]);
      *reinterpret_cast<float4*>(op + 16*m + 4*g) = v;
    }
  }
}

extern "C" void kernel_launch(void* const* d_in, const int* in_sizes, int n_in,
                              void* d_out, int out_size, void* d_ws, size_t ws_size,
                              hipStream_t stream) {
  const float* z  = (const float*)d_in[0];
  const float* W1 = (const float*)d_in[1];
  const float* b1 = (const float*)d_in[2];
  const float* W2 = (const float*)d_in[3];
  const float* b2 = (const float*)d_in[4];
  float* out = (float*)d_out;

  hipLaunchKernelGGL(veronese_fused, dim3(BLOCKS), dim3(BLOCK), 0, stream,
                     z, W1, b1, W2, b2, out);
}

// Round 9
// 141.200 us; speedup vs baseline: 1.6055x; 1.0729x over previous
//
#include <hip/hip_runtime.h>
#include <stdint.h>

#define NROWS 262144
#define INF   64
#define HIDN  256
#define OUTM  60
#define BLOCKS 512
#define BLOCK  1024                // 16 waves x 32 rows = 512 rows/block

typedef __attribute__((ext_vector_type(8))) short bf16x8;
typedef __attribute__((ext_vector_type(4))) float f32x4;

// 2x f32 -> packed bf16 (RNE), 1 instruction
__device__ __forceinline__ uint32_t pk2(float lo, float hi) {
  uint32_t r;
  asm("v_cvt_pk_bf16_f32 %0, %1, %2" : "=v"(r) : "v"(lo), "v"(hi));
  return r;
}

union U8 { uint32_t u[4]; bf16x8 v; uint4 q; };

// ---------------------------------------------------------------------------
// Fused kernel, round 9 layout:
//  - 1024-thr block (16 waves), each wave owns 32 rows for the MLP (t=0,1):
//    per-wave regs ~halved vs R8 (acc2 32, zf 16) -> total w/ AGPR <=128
//    -> 4 waves/SIMD = 16 waves/CU (R4/R8 were stuck at ~8: VGPR_Count
//    excludes the 64-AGPR accumulator; ~168 total -> 2 waves/SIMD).
//  - Paired Jacobi: waves 0-7 compute quats for 64 rows each (full-lane
//    utilization, half the total quat VALU issue) -> LDS qbuf; waves 8-15
//    start MFMA work immediately -> VALU (Jacobi) and MFMA pipes overlap.
//  - LDS: W1T [256][64] bf16 @0 (128B rows), W2T [64][256] bf16 @32768
//    (512B rows, rows 0-3 zero = quat slot), both XOR-swizzled ((row&7)<<4)
//    on 16B units; qbuf 512x float4 @65536.
// ---------------------------------------------------------------------------
__global__ __launch_bounds__(BLOCK, 1)
void veronese_fused(const float* __restrict__ z,  const float* __restrict__ W1,
                    const float* __restrict__ b1, const float* __restrict__ W2,
                    const float* __restrict__ b2, float* __restrict__ out) {
  __shared__ __align__(16) uint8_t lds[65536 + 8192];
  const int tid = threadIdx.x;

  // ---- stage W1T: 4 threads per hid row, 2x16B chunks each ----
  {
    const int hid = tid & 255;
    const int q4  = tid >> 8;           // 0..3
    #pragma unroll
    for (int cc = 0; cc < 2; ++cc) {
      const int hc = q4 * 2 + cc;       // 16B chunk (8 in-values)
      float f[8];
      #pragma unroll
      for (int j = 0; j < 8; ++j) f[j] = W1[(hc*8 + j) * HIDN + hid];
      U8 u;
      u.u[0] = pk2(f[0], f[1]); u.u[1] = pk2(f[2], f[3]);
      u.u[2] = pk2(f[4], f[5]); u.u[3] = pk2(f[6], f[7]);
      uint32_t off = (uint32_t)hid * 128 + (uint32_t)((hc * 16) ^ ((hid & 7) << 4));
      *reinterpret_cast<uint4*>(lds + off) = u.q;
    }
  }
  // ---- stage W2T: 16 threads per out row, 2x16B chunks; rows 0-3 zero ----
  {
    const int o   = tid & 63;
    const int seg = tid >> 6;           // 0..15
    #pragma unroll
    for (int uu = 0; uu < 2; ++uu) {
      const int hb = seg * 16 + uu * 8; // hid base of this 16B chunk
      float f[8];
      #pragma unroll
      for (int j = 0; j < 8; ++j)
        f[j] = (o >= 4) ? W2[(hb + j) * OUTM + (o - 4)] : 0.0f;
      U8 u;
      u.u[0] = pk2(f[0], f[1]); u.u[1] = pk2(f[2], f[3]);
      u.u[2] = pk2(f[4], f[5]); u.u[3] = pk2(f[6], f[7]);
      uint32_t off = 32768u + (uint32_t)o * 512 + (uint32_t)((hb * 2) ^ ((o & 7) << 4));
      *reinterpret_cast<uint4*>(lds + off) = u.q;
    }
  }
  __syncthreads();

  const int l   = tid & 63;
  const int w   = tid >> 6;             // 0..15
  const int g   = l >> 4;
  const int l15 = l & 15;
  const uint32_t swz = (uint32_t)((l & 7) << 4);
  // 4-slot exchange lane addresses (verified round 3)
  const int srcA = l15 + 32*(g & 1) + 16*(g >> 1);
  const int srcB = l15 + 32*(g & 1) + 16*(1 - (g >> 1));
  const bool hiq = (g & 2) != 0;
  const bool amI16 = (l & 16) != 0;

  // bias2: out col = 16m+4g; col<4 is the quat slot (zero bias)
  f32x4 bias2[4];
  #pragma unroll
  for (int m = 0; m < 4; ++m) {
    int ob = 16*m + 4*g;
    if (ob >= 4) bias2[m] = *reinterpret_cast<const f32x4*>(b2 + ob - 4);
    else         bias2[m] = (f32x4){0.f, 0.f, 0.f, 0.f};
  }

  const int blockRow = blockIdx.x * (BLOCK / 2);   // 512 rows per block
  const int rowBase  = blockRow + w * 32;          // this wave's MLP rows

  // ---- z B-fragments for the 2 row-tiles ----
  bf16x8 zf[2][2];
  #pragma unroll
  for (int t = 0; t < 2; ++t) {
    const float* zp = z + (size_t)(rowBase + 16*t + l15) * INF;
    #pragma unroll
    for (int k1 = 0; k1 < 2; ++k1) {
      float4 a0 = *reinterpret_cast<const float4*>(zp + k1*32 + 8*g);
      float4 a1 = *reinterpret_cast<const float4*>(zp + k1*32 + 8*g + 4);
      U8 u;
      u.u[0] = pk2(a0.x, a0.y); u.u[1] = pk2(a0.z, a0.w);
      u.u[2] = pk2(a1.x, a1.y); u.u[3] = pk2(a1.z, a1.w);
      zf[t][k1] = u.v;
    }
  }

  // ---- paired Jacobi: waves 0-7 each solve 64 rows -> LDS qbuf ----
  if (w < 8) {
    const float* zq = z + (size_t)(blockRow + w * 64 + l) * INF;
    float4 qv0 = reinterpret_cast<const float4*>(zq)[0];
    float4 qv1 = reinterpret_cast<const float4*>(zq)[1];
    float4 qv2 = reinterpret_cast<const float4*>(zq)[2];
    float zv[10] = {qv0.x,qv0.y,qv0.z,qv0.w, qv1.x,qv1.y,qv1.z,qv1.w,
                    qv2.x,qv2.y};
    float M[4][4];
    M[0][0]=zv[0]; M[0][1]=zv[1]; M[0][2]=zv[2]; M[0][3]=zv[3];
    M[1][1]=zv[4]; M[1][2]=zv[5]; M[1][3]=zv[6];
    M[2][2]=zv[7]; M[2][3]=zv[8]; M[3][3]=zv[9];
    M[1][0]=zv[1]; M[2][0]=zv[2]; M[3][0]=zv[3];
    M[2][1]=zv[5]; M[3][1]=zv[6]; M[3][2]=zv[8];
    float V[4][4] = {{1.f,0.f,0.f,0.f},{0.f,1.f,0.f,0.f},
                     {0.f,0.f,1.f,0.f},{0.f,0.f,0.f,1.f}};

#define JROT(p, q) do {                                                      \
    float apq = M[p][q];                                                     \
    float app = M[p][p], aqq = M[q][q];                                      \
    float tau = (aqq - app) * (0.5f * __builtin_amdgcn_rcpf(apq));           \
    float t_r = copysignf(1.0f, tau) *                                       \
        __builtin_amdgcn_rcpf(fabsf(tau) +                                   \
            __builtin_amdgcn_sqrtf(fmaf(tau, tau, 1.0f)));                   \
    float t   = (fabsf(apq) > 1e-25f) ? t_r : 0.0f;                          \
    float c   = __builtin_amdgcn_rsqf(fmaf(t, t, 1.0f));                     \
    float s   = t * c;                                                       \
    M[p][p] = fmaf(-t, apq, app);                                            \
    M[q][q] = fmaf( t, apq, aqq);                                            \
    M[p][q] = 0.0f; M[q][p] = 0.0f;                                          \
    _Pragma("unroll")                                                        \
    for (int r = 0; r < 4; ++r) {                                            \
      if (r != p && r != q) {                                                \
        float arp = M[r][p], arq = M[r][q];                                  \
        float nrp = fmaf(-s, arq, c * arp);                                  \
        float nrq = fmaf( s, arp, c * arq);                                  \
        M[r][p] = nrp; M[p][r] = nrp;                                        \
        M[r][q] = nrq; M[q][r] = nrq;                                        \
      }                                                                      \
    }                                                                        \
    _Pragma("unroll")                                                        \
    for (int r = 0; r < 4; ++r) {                                            \
      float vrp = V[r][p], vrq = V[r][q];                                    \
      V[r][p] = fmaf(-s, vrq, c * vrp);                                      \
      V[r][q] = fmaf( s, vrp, c * vrq);                                      \
    }                                                                        \
  } while (0)

    #pragma unroll
    for (int sweep = 0; sweep < 6; ++sweep) {
      JROT(0, 1); JROT(0, 2); JROT(0, 3);
      JROT(1, 2); JROT(1, 3); JROT(2, 3);
    }
#undef JROT

    float bv = M[0][0];
    float q0 = V[0][0], q1 = V[1][0], q2 = V[2][0], q3 = V[3][0];
    #pragma unroll
    for (int j = 1; j < 4; ++j) {
      float dj = M[j][j];
      bool  b  = dj > bv;
      bv = b ? dj      : bv;
      q0 = b ? V[0][j] : q0;
      q1 = b ? V[1][j] : q1;
      q2 = b ? V[2][j] : q2;
      q3 = b ? V[3][j] : q3;
    }
    float sgn = (q0 < 0.0f) ? -1.0f : 1.0f;  // sign(0) -> +1
    float4 qq = make_float4(q0*sgn, q1*sgn, q2*sgn, q3*sgn);
    *reinterpret_cast<float4*>(lds + 65536 + (uint32_t)(w*64 + l) * 16) = qq;
  }

  // ---- MLP (all 16 waves) ----
  f32x4 acc2[2][4];
  #pragma unroll
  for (int t = 0; t < 2; ++t)
    #pragma unroll
    for (int m = 0; m < 4; ++m) acc2[t][m] = bias2[m];

  for (int ks = 0; ks < 8; ++ks) {
    uint32_t c[2][4];
    // layer 1, two hid m-tiles (mm), A-frags shared across the 2 z-tiles
    #pragma unroll
    for (int mm = 0; mm < 2; ++mm) {
      const int hb = 16*(2*ks + mm) + 4*g;
      f32x4 bv = *reinterpret_cast<const f32x4*>(b1 + hb);   // L1-hot
      uint32_t rowb = (uint32_t)(16*(2*ks+mm) + l15) * 128;
      bf16x8 a0 = *reinterpret_cast<const bf16x8*>(
          lds + rowb + (((uint32_t)(16*g)) ^ swz));
      bf16x8 a1 = *reinterpret_cast<const bf16x8*>(
          lds + rowb + (((uint32_t)(64 + 16*g)) ^ swz));
      f32x4 acc1[2];
      __builtin_amdgcn_s_setprio(1);
      #pragma unroll
      for (int t = 0; t < 2; ++t) {
        acc1[t] = __builtin_amdgcn_mfma_f32_16x16x32_bf16(a0, zf[t][0], bv, 0,0,0);
        acc1[t] = __builtin_amdgcn_mfma_f32_16x16x32_bf16(a1, zf[t][1], acc1[t], 0,0,0);
      }
      __builtin_amdgcn_s_setprio(0);
      #pragma unroll
      for (int t = 0; t < 2; ++t) {
        float h0 = fmaxf(acc1[t][0], 0.f), h1 = fmaxf(acc1[t][1], 0.f);
        float h2 = fmaxf(acc1[t][2], 0.f), h3 = fmaxf(acc1[t][3], 0.f);
        c[t][2*mm+0] = pk2(h0, h1);
        c[t][2*mm+1] = pk2(h2, h3);
      }
    }
    // layer-2 A-frags (shared across tiles)
    bf16x8 a2[4];
    #pragma unroll
    for (int m = 0; m < 4; ++m) {
      uint32_t rowb = 32768u + (uint32_t)(16*m + l15) * 512;
      a2[m] = *reinterpret_cast<const bf16x8*>(
          lds + rowb + (((uint32_t)(64*ks + 16*g)) ^ swz));
    }
    // exchange + layer 2 per tile: 4 shuffles (slot scheme), 8 cndmask
    #pragma unroll
    for (int t = 0; t < 2; ++t) {
      uint32_t v02a = amI16 ? c[t][2] : c[t][0];
      uint32_t v13a = amI16 ? c[t][3] : c[t][1];
      uint32_t v02b = amI16 ? c[t][0] : c[t][2];
      uint32_t v13b = amI16 ? c[t][1] : c[t][3];
      uint32_t s0 = (uint32_t)__shfl((int)v02a, srcA, 64);
      uint32_t s1 = (uint32_t)__shfl((int)v13a, srcA, 64);
      uint32_t s2 = (uint32_t)__shfl((int)v02b, srcB, 64);
      uint32_t s3 = (uint32_t)__shfl((int)v13b, srcB, 64);
      U8 bu;
      bu.u[0] = hiq ? s2 : s0;
      bu.u[1] = hiq ? s3 : s1;
      bu.u[2] = hiq ? s0 : s2;
      bu.u[3] = hiq ? s1 : s3;
      __builtin_amdgcn_s_setprio(1);
      #pragma unroll
      for (int m = 0; m < 4; ++m)
        acc2[t][m] = __builtin_amdgcn_mfma_f32_16x16x32_bf16(a2[m], bu.v, acc2[t][m], 0,0,0);
      __builtin_amdgcn_s_setprio(0);
    }
  }

  // ---- quats ready? inject into out cols 0-3 (g==0 lanes, acc2[t][0]) ----
  __syncthreads();
  #pragma unroll
  for (int t = 0; t < 2; ++t) {
    if (g == 0) {
      f32x4 qv = *reinterpret_cast<const f32x4*>(
          lds + 65536 + (uint32_t)(w*32 + 16*t + l15) * 16);
      acc2[t][0] = qv;
    }
  }

  // ---- store: full 256B lines per row, no RMW ----
  #pragma unroll
  for (int t = 0; t < 2; ++t) {
    float* op = out + (size_t)(rowBase + 16*t + l15) * 64;
    #pragma unroll
    for (int m = 0; m < 4; ++m) {
      float4 v = make_float4(acc2[t][m][0], acc2[t][m][1],
                             acc2[t][m][2], acc2[t][m][3]);
      *reinterpret_cast<float4*>(op + 16*m + 4*g) = v;
    }
  }
}

extern "C" void kernel_launch(void* const* d_in, const int* in_sizes, int n_in,
                              void* d_out, int out_size, void* d_ws, size_t ws_size,
                              hipStream_t stream) {
  const float* z  = (const float*)d_in[0];
  const float* W1 = (const float*)d_in[1];
  const float* b1 = (const float*)d_in[2];
  const float* W2 = (const float*)d_in[3];
  const float* b2 = (const float*)d_in[4];
  float* out = (float*)d_out;

  hipLaunchKernelGGL(veronese_fused, dim3(BLOCKS), dim3(BLOCK), 0, stream,
                     z, W1, b1, W2, b2, out);
}